// Round 9
// baseline (331.686 us; speedup 1.0000x reference)
//
#include <hip/hip_runtime.h>
#include <stdint.h>

// ---------------------------------------------------------------------------
// MultiGraph hetero-GNN + gumbel-top-k edge pruning, fp32 throughout.
// Round 16 (from r13 @ 316.0us best; r14/r15 regressions reverted):
//  fused_layer GEMM consumer re-partitioned: wave owns 8 m-rows x 32 cols
//  (m=lane>>3, colq=wv*8+(lane&7)) instead of 2 m-rows x 128 cols. A wave's
//  Ws read per k is now 128B distinct (8-way broadcast) instead of the full
//  1KB row -> ~4x less LDS read traffic. Cycle model: GEMM was LDS-pipe
//  bound (~9.7K cy/block, 4x redundant W reads across waves) -- explains
//  why occupancy (r14), barriers (r11), and pipelining (r15) were all
//  neutral: LDS throughput is a shared per-CU resource.
//  Each output keeps its exact (part, chunk, k)-ascending FMA chain (only
//  the owning lane changes) -> bit-exact.
//  Agg: r13 simple 8-unroll (r15 pipeline reverted, was neutral).
//  W staging/prefetch (r12) unchanged. row_topk r13 / scatter / final
//  verbatim.
// PRNG: JAX threefry2x32, partitionable path (verified absmax=0.0 r1-r15).
// ---------------------------------------------------------------------------

namespace {

constexpr int NPn = 4096;
constexpr int NAn = 2048;
constexpr int Hh  = 128;
constexpr int EPPc = 131072;
constexpr int EAAc = 65536;
constexpr int KSEL = 5;
constexpr int BSLOT = 128;   // bucket capacity per node (deg<128: Poisson-32, e^-85 tail)

// bucket segments (cnt index = co + node; entries base = (co+node)*128):
// 0: pp-dst (4096)   4096: aa-dst (2048)   6144: pa-dst (2048)
// 8192: ap-dst (4096) 12288: pp-src (4096) 16384: aa-src (2048)
// payloads: pp: (other<<18)|e  aa: (other<<16)|e  pa/ap: src only

__host__ __device__ static inline void tf2x32(uint32_t k0, uint32_t k1,
                                              uint32_t& x0, uint32_t& x1) {
  uint32_t ks2 = k0 ^ k1 ^ 0x1BD11BDAu;
  x0 += k0; x1 += k1;
#define TF_R(r) { x0 += x1; x1 = (x1 << (r)) | (x1 >> (32 - (r))); x1 ^= x0; }
  TF_R(13) TF_R(15) TF_R(26) TF_R(6)
  x0 += k1;  x1 += ks2 + 1u;
  TF_R(17) TF_R(29) TF_R(16) TF_R(24)
  x0 += ks2; x1 += k0 + 2u;
  TF_R(13) TF_R(15) TF_R(26) TF_R(6)
  x0 += k0;  x1 += k1 + 3u;
  TF_R(17) TF_R(29) TF_R(16) TF_R(24)
  x0 += k1;  x1 += ks2 + 4u;
  TF_R(13) TF_R(15) TF_R(26) TF_R(6)
  x0 += ks2; x1 += k0 + 5u;
#undef TF_R
}

// ---------------- bucket scatter (r7 verbatim) ----------------
__global__ __launch_bounds__(256) void scatter_kernel(
    const int* src_pp, const int* dst_pp, const int* src_aa, const int* dst_aa,
    const int* src_pa, const int* dst_pa, const int* src_ap, const int* dst_ap,
    int* cnt, int* entries)
{
  int i = blockIdx.x * 256 + threadIdx.x;
  int key, pl;
  if (i < 131072) {                       // pp by dst
    int e = i;
    key = 0 + dst_pp[e]; pl = (src_pp[e] << 18) | e;
  } else if (i < 196608) {                // aa by dst
    int e = i - 131072;
    key = 4096 + dst_aa[e]; pl = (src_aa[e] << 16) | e;
  } else if (i < 327680) {                // pa by dst (payload = src paper)
    int e = i - 196608;
    key = 6144 + dst_pa[e]; pl = src_pa[e];
  } else if (i < 458752) {                // ap by dst (payload = src author)
    int e = i - 327680;
    key = 8192 + dst_ap[e]; pl = src_ap[e];
  } else if (i < 589824) {                // pp by src (payload = (dst<<18)|e)
    int e = i - 458752;
    key = 12288 + src_pp[e]; pl = (dst_pp[e] << 18) | e;
  } else if (i < 655360) {                // aa by src
    int e = i - 589824;
    key = 16384 + src_aa[e]; pl = (dst_aa[e] << 16) | e;
  } else return;
  int pos = atomicAdd(&cnt[key], 1);
  if (pos < BSLOT) entries[key * BSLOT + pos] = pl;
}

// ---------------- fused agg + GEMM (+ optional P projections) --------------------------
// r16: 8 nodes per block. Agg: r13 half-wave-per-node 8-unroll. GEMM: Ws
// chunks with register prefetch (r12); consumer wave-partitioned by COLUMN
// (m=lane>>3, colq=wv*8+(lane&7)) so Ws reads broadcast 8-way -> 4x less
// LDS read traffic. P stage: r9 body (handoff write re-indexed).
struct FDesc {
  const float* gsrc; const float* wArr; int cntOff; int shift;
  float* Mout;                                  // agg-only output (when W0 == null)
  const float* Aself; const float* W0; const float* W1;
  const float* A2;  const float* W2;            // optional part 2
  float* C; int relu;                           // C may be null (P-only)
  const float* WP; float* P1; float* P2;        // optional P stage
};
struct FArgs { FDesc d[4]; int bstart[5]; int nd; };

__global__ __launch_bounds__(256) void fused_layer(FArgs fa, const int* __restrict__ cnt,
                                                   const int* __restrict__ entries)
{
  __shared__ __align__(16) float Xs[8][128];
  __shared__ __align__(16) float Ms[8][128];
  __shared__ __align__(16) float Zs[8][128];
  __shared__ __align__(16) float Ws[32][128];
  int blk = blockIdx.x, tid = threadIdx.x;
  int di = 0;
  while (di < fa.nd - 1 && blk >= fa.bstart[di + 1]) ++di;
  FDesc D = fa.d[di];
  int node0 = (blk - fa.bstart[di]) * 8;
  // ---- agg phase (r13: half-wave per node, 8-unrolled) ----
  {
    int hw = tid >> 5;
    int node = node0 + hw;
    int fl = (tid & 31) << 2;
    int deg = cnt[D.cntOff + node];
    const int* ent = entries + (size_t)(D.cntOff + node) * BSLOT;
    const float* h = D.gsrc;
    int sh = D.shift;
    float ax = 0.f, ay = 0.f, az = 0.f, aw = 0.f;
    if (D.wArr) {
      unsigned mask = (1u << sh) - 1u;
      int k = 0;
      for (; k + 3 < deg; k += 4) {
        unsigned p0 = (unsigned)ent[k], p1 = (unsigned)ent[k + 1];
        unsigned p2 = (unsigned)ent[k + 2], p3 = (unsigned)ent[k + 3];
        float w0 = D.wArr[p0 & mask], w1 = D.wArr[p1 & mask];
        float w2v = D.wArr[p2 & mask], w3 = D.wArr[p3 & mask];
        float4 v0, v1, v2, v3;
        if (w0 != 0.f) v0 = *(const float4*)&h[(size_t)(p0 >> sh) * Hh + fl];
        if (w1 != 0.f) v1 = *(const float4*)&h[(size_t)(p1 >> sh) * Hh + fl];
        if (w2v != 0.f) v2 = *(const float4*)&h[(size_t)(p2 >> sh) * Hh + fl];
        if (w3 != 0.f) v3 = *(const float4*)&h[(size_t)(p3 >> sh) * Hh + fl];
        if (w0 != 0.f) { ax += v0.x; ay += v0.y; az += v0.z; aw += v0.w; }
        if (w1 != 0.f) { ax += v1.x; ay += v1.y; az += v1.z; aw += v1.w; }
        if (w2v != 0.f) { ax += v2.x; ay += v2.y; az += v2.z; aw += v2.w; }
        if (w3 != 0.f) { ax += v3.x; ay += v3.y; az += v3.z; aw += v3.w; }
      }
      for (; k < deg; ++k) {
        unsigned pl = (unsigned)ent[k];
        float wt = D.wArr[pl & mask];
        if (wt != 0.f) {
          float4 v = *(const float4*)&h[(size_t)(pl >> sh) * Hh + fl];
          ax += v.x; ay += v.y; az += v.z; aw += v.w;
        }
      }
    } else {
      int k = 0;
      for (; k + 7 < deg; k += 8) {
        unsigned p0 = (unsigned)ent[k],     p1 = (unsigned)ent[k + 1];
        unsigned p2 = (unsigned)ent[k + 2], p3 = (unsigned)ent[k + 3];
        unsigned p4 = (unsigned)ent[k + 4], p5 = (unsigned)ent[k + 5];
        unsigned p6 = (unsigned)ent[k + 6], p7 = (unsigned)ent[k + 7];
        float4 v0 = *(const float4*)&h[(size_t)(p0 >> sh) * Hh + fl];
        float4 v1 = *(const float4*)&h[(size_t)(p1 >> sh) * Hh + fl];
        float4 v2 = *(const float4*)&h[(size_t)(p2 >> sh) * Hh + fl];
        float4 v3 = *(const float4*)&h[(size_t)(p3 >> sh) * Hh + fl];
        float4 v4 = *(const float4*)&h[(size_t)(p4 >> sh) * Hh + fl];
        float4 v5 = *(const float4*)&h[(size_t)(p5 >> sh) * Hh + fl];
        float4 v6 = *(const float4*)&h[(size_t)(p6 >> sh) * Hh + fl];
        float4 v7 = *(const float4*)&h[(size_t)(p7 >> sh) * Hh + fl];
        ax += v0.x; ay += v0.y; az += v0.z; aw += v0.w;
        ax += v1.x; ay += v1.y; az += v1.z; aw += v1.w;
        ax += v2.x; ay += v2.y; az += v2.z; aw += v2.w;
        ax += v3.x; ay += v3.y; az += v3.z; aw += v3.w;
        ax += v4.x; ay += v4.y; az += v4.z; aw += v4.w;
        ax += v5.x; ay += v5.y; az += v5.z; aw += v5.w;
        ax += v6.x; ay += v6.y; az += v6.z; aw += v6.w;
        ax += v7.x; ay += v7.y; az += v7.z; aw += v7.w;
      }
      for (; k < deg; ++k) {
        unsigned pl = (unsigned)ent[k];
        float4 v = *(const float4*)&h[(size_t)(pl >> sh) * Hh + fl];
        ax += v.x; ay += v.y; az += v.z; aw += v.w;
      }
    }
    float cd = fmaxf((float)deg, 1.0f);
    float4 o; o.x = ax / cd; o.y = ay / cd; o.z = az / cd; o.w = aw / cd;
    if (D.W0 == nullptr) {
      *(float4*)&D.Mout[(size_t)node * Hh + fl] = o;
    } else {
      *(float4*)&Ms[hw][fl] = o;
    }
  }
  if (D.W0 == nullptr) return;   // agg-only block (uniform per block)
  // ---- stage self rows (and part-2 rows): contiguous, coalesced ----
  {
    int rm = tid >> 5, cq = (tid & 31) << 2;
    *(float4*)&Xs[rm][cq] = *(const float4*)&D.Aself[(size_t)(node0 + rm) * 128 + cq];
    if (D.A2)
      *(float4*)&Zs[rm][cq] = *(const float4*)&D.A2[(size_t)(node0 + rm) * 128 + cq];
  }
  // ---- GEMM: wave-column-partitioned consumer. Thread -> (m = lane>>3,
  // colq = wv*8 + (lane&7)); 4 outputs C[m][colq*4..+3]. Ws reads per k are
  // 128B distinct per wave (8-way lane broadcast). Chain order: part-major,
  // chunk, k ascending (== r13 per output -> bit-exact).
  int lane = tid & 63;
  int m = lane >> 3;
  int colq = ((tid >> 6) << 3) | (lane & 7);
  int r = tid >> 3, f = (tid & 7) << 4;
  float4 accv = {0.f, 0.f, 0.f, 0.f};
  int parts = D.A2 ? 3 : 2;
  int T = parts * 4;
  float4 g0, g1, g2, g3;
  {
    const float* srcp = &D.W0[(size_t)r * 128 + f];       // chunk 0: rows 0..31
    g0 = *(const float4*)&srcp[0];
    g1 = *(const float4*)&srcp[4];
    g2 = *(const float4*)&srcp[8];
    g3 = *(const float4*)&srcp[12];
  }
  for (int t = 0; t < T; ++t) {
    __syncthreads();                     // chunk t-1 consumed / agg+stage visible
    *(float4*)&Ws[r][f]      = g0;
    *(float4*)&Ws[r][f + 4]  = g1;
    *(float4*)&Ws[r][f + 8]  = g2;
    *(float4*)&Ws[r][f + 12] = g3;
    if (t + 1 < T) {                     // issue chunk t+1 loads; land under compute
      int p2 = (t + 1) >> 2, ci = (t + 1) & 3;
      const float* Wn = (p2 == 0) ? D.W0 : (p2 == 1) ? D.W1 : D.W2;
      const float* srcp = &Wn[(size_t)(ci * 32 + r) * 128 + f];
      g0 = *(const float4*)&srcp[0];
      g1 = *(const float4*)&srcp[4];
      g2 = *(const float4*)&srcp[8];
      g3 = *(const float4*)&srcp[12];
    }
    __syncthreads();                     // Ws chunk t visible
    int p = t >> 2, c = t & 3;
#define KCHUNK(AR)                                              \
    _Pragma("unroll")                                           \
    for (int k4 = 0; k4 < 32; k4 += 4) {                        \
      float4 av = *(const float4*)&AR[m][c * 32 + k4];          \
      float4 w0 = *(const float4*)&Ws[k4 + 0][colq << 2];       \
      float4 w1 = *(const float4*)&Ws[k4 + 1][colq << 2];       \
      float4 w2v = *(const float4*)&Ws[k4 + 2][colq << 2];      \
      float4 w3 = *(const float4*)&Ws[k4 + 3][colq << 2];       \
      accv.x += av.x * w0.x; accv.y += av.x * w0.y;             \
      accv.z += av.x * w0.z; accv.w += av.x * w0.w;             \
      accv.x += av.y * w1.x; accv.y += av.y * w1.y;             \
      accv.z += av.y * w1.z; accv.w += av.y * w1.w;             \
      accv.x += av.z * w2v.x; accv.y += av.z * w2v.y;           \
      accv.z += av.z * w2v.z; accv.w += av.z * w2v.w;           \
      accv.x += av.w * w3.x; accv.y += av.w * w3.y;             \
      accv.z += av.w * w3.z; accv.w += av.w * w3.w;             \
    }
    if (p == 0) { KCHUNK(Xs) } else if (p == 1) { KCHUNK(Ms) } else { KCHUNK(Zs) }
#undef KCHUNK
  }
  if (D.relu) {
    accv.x = fmaxf(accv.x, 0.f); accv.y = fmaxf(accv.y, 0.f);
    accv.z = fmaxf(accv.z, 0.f); accv.w = fmaxf(accv.w, 0.f);
  }
  if (D.C)
    *(float4*)&D.C[(size_t)(node0 + m) * 128 + (colq << 2)] = accv;
  if (D.WP == nullptr) return;
  // ---- P stage: h rows -> LDS (reuse Xs), then P1/P2 = h @ WP halves.
  // r9 body (handoff write re-indexed to (m, colq)); k ascending -> bit-exact.
  __syncthreads();
  *(float4*)&Xs[m][colq << 2] = accv;
  __syncthreads();
  {
    int half = tid >> 7;                 // 0 -> P1 (WP rows 0..127), 1 -> P2 (rows 128..255)
    int rg = (tid >> 6) & 1;             // row quad: rows rg*4 .. rg*4+3
    int c0 = (tid & 63) << 2;            // 4 cols
    const float* Wb = D.WP + ((size_t)(half ? 128 : 0)) * 256 + c0;
    float4 acc0 = {0,0,0,0}, acc1 = {0,0,0,0}, acc2 = {0,0,0,0}, acc3 = {0,0,0,0};
    for (int k = 0; k < 128; k += 2) {
      float4 w0 = *(const float4*)&Wb[(size_t)k * 256];
      float4 w1 = *(const float4*)&Wb[(size_t)(k + 1) * 256];
      float2 a0 = *(const float2*)&Xs[rg * 4 + 0][k];
      float2 a1 = *(const float2*)&Xs[rg * 4 + 1][k];
      float2 a2 = *(const float2*)&Xs[rg * 4 + 2][k];
      float2 a3 = *(const float2*)&Xs[rg * 4 + 3][k];
      acc0.x += a0.x * w0.x; acc0.y += a0.x * w0.y; acc0.z += a0.x * w0.z; acc0.w += a0.x * w0.w;
      acc0.x += a0.y * w1.x; acc0.y += a0.y * w1.y; acc0.z += a0.y * w1.z; acc0.w += a0.y * w1.w;
      acc1.x += a1.x * w0.x; acc1.y += a1.x * w0.y; acc1.z += a1.x * w0.z; acc1.w += a1.x * w0.w;
      acc1.x += a1.y * w1.x; acc1.y += a1.y * w1.y; acc1.z += a1.y * w1.z; acc1.w += a1.y * w1.w;
      acc2.x += a2.x * w0.x; acc2.y += a2.x * w0.y; acc2.z += a2.x * w0.z; acc2.w += a2.x * w0.w;
      acc2.x += a2.y * w1.x; acc2.y += a2.y * w1.y; acc2.z += a2.y * w1.z; acc2.w += a2.y * w1.w;
      acc3.x += a3.x * w0.x; acc3.y += a3.x * w0.y; acc3.z += a3.x * w0.z; acc3.w += a3.x * w0.w;
      acc3.x += a3.y * w1.x; acc3.y += a3.y * w1.y; acc3.z += a3.y * w1.z; acc3.w += a3.y * w1.w;
    }
    float* Pout = half ? D.P2 : D.P1;
    *(float4*)&Pout[(size_t)(node0 + rg * 4 + 0) * 256 + c0] = acc0;
    *(float4*)&Pout[(size_t)(node0 + rg * 4 + 1) * 256 + c0] = acc1;
    *(float4*)&Pout[(size_t)(node0 + rg * 4 + 2) * 256 + c0] = acc2;
    *(float4*)&Pout[(size_t)(node0 + rg * 4 + 3) * 256 + c0] = acc3;
  }
}

// ---------------- fused edge-MLP + sparse coalesce + masked gumbel top-5 ----------------
// r13 verbatim: coalesce loop reads dS/pS via LDS broadcast; deg<=64 fast
// path. MLP 8-edge unroll / reduce tree / sel5 protocol verbatim.
__global__ __launch_bounds__(256) void row_topk(
    const float* __restrict__ P1pp, const float* __restrict__ P2pp,
    const float* __restrict__ b1pp, const float* __restrict__ W2pp,
    const float* __restrict__ b2pp,
    const float* __restrict__ P1aa, const float* __restrict__ P2aa,
    const float* __restrict__ b1aa, const float* __restrict__ W2aa,
    const float* __restrict__ b2aa,
    const int* __restrict__ cnt, const int* __restrict__ entries,
    float* __restrict__ w_pp, float* __restrict__ w_aa,
    uint32_t kpp0, uint32_t kpp1, uint32_t kaa0, uint32_t kaa1)
{
  __shared__ int   dS[4][128];
  __shared__ float pS[4][128];
  __shared__ int   sel5[4][KSEL];
  int blk = blockIdx.x, tid = threadIdx.x;
  int lane = tid & 63, wv = tid >> 6;
  int row, Ncols, shift;
  int co; unsigned mask;
  const float* P1; const float* P2; const float* b1; const float* W2; const float* b2;
  float* wout; uint32_t k0, k1;
  if (blk < NPn / 4) {
    row = blk * 4 + wv; Ncols = NPn; shift = 18; mask = 0x3FFFFu; co = 12288;
    P1 = P1pp; P2 = P2pp; b1 = b1pp; W2 = W2pp; b2 = b2pp;
    wout = w_pp; k0 = kpp0; k1 = kpp1;
  } else {
    row = (blk - NPn / 4) * 4 + wv; Ncols = NAn; shift = 16; mask = 0xFFFFu; co = 16384;
    P1 = P1aa; P2 = P2aa; b1 = b1aa; W2 = W2aa; b2 = b2aa;
    wout = w_aa; k0 = kaa0; k1 = kaa1;
  }
  const int* ent = entries + (size_t)(co + row) * BSLOT;
  int deg = cnt[co + row];
  int j = lane << 2;
  // per-lane register staging (each lane only ever touches its j..j+3 slice)
  float4 p1v = *(const float4*)&P1[(size_t)row * 256 + j];
  float4 b1v = *(const float4*)&b1[j];
  float wa = W2[(j + 0) * 2], wb = W2[(j + 1) * 2];
  float wc = W2[(j + 2) * 2], wd = W2[(j + 3) * 2];
  float bias2 = b2[0];
  float pa = p1v.x, pb = p1v.y, pc = p1v.z, pd = p1v.w;
  float ba = b1v.x, bb = b1v.y, bc_ = b1v.z, bd = b1v.w;
#define SCORE(q) (fmaxf(pa + q.x + ba, 0.f) * wa + fmaxf(pb + q.y + bb, 0.f) * wb + \
                  fmaxf(pc + q.z + bc_, 0.f) * wc + fmaxf(pd + q.w + bd, 0.f) * wd)
  for (int k = 0; k < deg; k += 8) {
    int n = deg - k; if (n > 8) n = 8;
    unsigned pl0 = (unsigned)ent[k];
    unsigned pl1 = (n > 1) ? (unsigned)ent[k + 1] : pl0;
    unsigned pl2 = (n > 2) ? (unsigned)ent[k + 2] : pl0;
    unsigned pl3 = (n > 3) ? (unsigned)ent[k + 3] : pl0;
    unsigned pl4 = (n > 4) ? (unsigned)ent[k + 4] : pl0;
    unsigned pl5 = (n > 5) ? (unsigned)ent[k + 5] : pl0;
    unsigned pl6 = (n > 6) ? (unsigned)ent[k + 6] : pl0;
    unsigned pl7 = (n > 7) ? (unsigned)ent[k + 7] : pl0;
    int d0 = (int)(pl0 >> shift), d1 = (int)(pl1 >> shift);
    int d2 = (int)(pl2 >> shift), d3 = (int)(pl3 >> shift);
    int d4 = (int)(pl4 >> shift), d5 = (int)(pl5 >> shift);
    int d6 = (int)(pl6 >> shift), d7 = (int)(pl7 >> shift);
    float4 q0 = *(const float4*)&P2[(size_t)d0 * 256 + j];
    float4 q1 = *(const float4*)&P2[(size_t)d1 * 256 + j];
    float4 q2 = *(const float4*)&P2[(size_t)d2 * 256 + j];
    float4 q3 = *(const float4*)&P2[(size_t)d3 * 256 + j];
    float4 q4 = *(const float4*)&P2[(size_t)d4 * 256 + j];
    float4 q5 = *(const float4*)&P2[(size_t)d5 * 256 + j];
    float4 q6 = *(const float4*)&P2[(size_t)d6 * 256 + j];
    float4 q7 = *(const float4*)&P2[(size_t)d7 * 256 + j];
    float s0 = SCORE(q0), s1 = SCORE(q1), s2 = SCORE(q2), s3 = SCORE(q3);
    float s4 = SCORE(q4), s5 = SCORE(q5), s6 = SCORE(q6), s7 = SCORE(q7);
    for (int off = 32; off; off >>= 1) {
      s0 += __shfl_down(s0, off);
      s1 += __shfl_down(s1, off);
      s2 += __shfl_down(s2, off);
      s3 += __shfl_down(s3, off);
      s4 += __shfl_down(s4, off);
      s5 += __shfl_down(s5, off);
      s6 += __shfl_down(s6, off);
      s7 += __shfl_down(s7, off);
    }
    if (lane == 0) {
      dS[wv][k] = d0; pS[wv][k] = s0 + bias2;
      if (n > 1) { dS[wv][k + 1] = d1; pS[wv][k + 1] = s1 + bias2; }
      if (n > 2) { dS[wv][k + 2] = d2; pS[wv][k + 2] = s2 + bias2; }
      if (n > 3) { dS[wv][k + 3] = d3; pS[wv][k + 3] = s3 + bias2; }
      if (n > 4) { dS[wv][k + 4] = d4; pS[wv][k + 4] = s4 + bias2; }
      if (n > 5) { dS[wv][k + 5] = d5; pS[wv][k + 5] = s5 + bias2; }
      if (n > 6) { dS[wv][k + 6] = d6; pS[wv][k + 6] = s6 + bias2; }
      if (n > 7) { dS[wv][k + 7] = d7; pS[wv][k + 7] = s7 + bias2; }
    }
  }
#undef SCORE
  __syncthreads();
  if (deg > 0) {
    int   e0 = (lane < deg) ? dS[wv][lane] : -1;
    bool  two = (deg > 64);
    int   e1 = -1;
    if (two && 64 + lane < deg) e1 = dS[wv][64 + lane];
    float a0 = 0.f, a1 = 0.f;
    bool lead0 = (e0 >= 0), lead1 = (e1 >= 0);
    // LDS-broadcast coalesce (values/order identical to the shfl version:
    // pS[wv][j2] == __shfl(q0v/q1v, ...), j2 ascending -> bit-exact).
    if (!two) {
#pragma unroll 4
      for (int j2 = 0; j2 < deg; ++j2) {
        int bj = dS[wv][j2]; float bp = pS[wv][j2];
        if (bj == e0) { a0 += bp; if (j2 < lane) lead0 = false; }   // e0==-1 never matches
      }
    } else {
#pragma unroll 2
      for (int j2 = 0; j2 < deg; ++j2) {
        int bj = dS[wv][j2]; float bp = pS[wv][j2];
        if (e0 >= 0 && bj == e0) { a0 += bp; if (j2 < lane) lead0 = false; }
        if (e1 >= 0 && bj == e1) { a1 += bp; if (j2 < 64 + lane) lead1 = false; }
      }
    }
    uint32_t rowbase = (uint32_t)row * (uint32_t)Ncols;
    float y0 = -1e9f, y1 = -1e9f;
    bool c0 = lead0 && (a0 > 0.f);
    if (c0) {
      uint32_t x0 = 0u, x1 = rowbase + (uint32_t)e0;
      tf2x32(k0, k1, x0, x1);
      uint32_t bits = x0 ^ x1;
      float fv = __uint_as_float((bits >> 9) | 0x3f800000u) - 1.0f;
      float u = fmaxf(1e-10f, fv + 1e-10f);
      y0 = a0 + (-logf(-logf(u)));
    }
    bool c1 = lead1 && (a1 > 0.f);
    if (c1) {
      uint32_t x0 = 0u, x1 = rowbase + (uint32_t)e1;
      tf2x32(k0, k1, x0, x1);
      uint32_t bits = x0 ^ x1;
      float fv = __uint_as_float((bits >> 9) | 0x3f800000u) - 1.0f;
      float u = fmaxf(1e-10f, fv + 1e-10f);
      y1 = a1 + (-logf(-logf(u)));
    }
    int cnt2 = __popcll(__ballot(c0)) + __popcll(__ballot(c1));
    int nsel = cnt2 < KSEL ? cnt2 : KSEL;
    for (int it = 0; it < nsel; ++it) {
      float best; int bc;
      if (y1 > y0 || (y1 == y0 && (unsigned)e1 < (unsigned)e0)) { best = y1; bc = e1; }
      else { best = y0; bc = e0; }
      for (int mm = 32; mm; mm >>= 1) {
        float ov = __shfl_xor(best, mm); int oc = __shfl_xor(bc, mm);
        if (ov > best || (ov == best && (unsigned)oc < (unsigned)bc)) { best = ov; bc = oc; }
      }
      if (lane == 0) sel5[wv][it] = bc;
      if (e0 == bc) y0 = -3.0e38f;
      if (e1 == bc) y1 = -3.0e38f;
    }
    if (nsel < KSEL && lane == 0) {
      int c = 0;
      for (int it = nsel; it < KSEL; ++it) {
        for (;;) {
          bool used = false;
          for (int q = 0; q < it; ++q) used |= (sel5[wv][q] == c);
          if (!used) break;
          ++c;
        }
        sel5[wv][it] = c++;
      }
    }
  }
  __syncthreads();
  for (int k = lane; k < deg; k += 64) {
    unsigned pl = (unsigned)ent[k];
    int d = (int)(pl >> shift);
    int e = (int)(pl & mask);
    float v = 0.f;
#pragma unroll
    for (int q = 0; q < KSEL; ++q) v = (sel5[wv][q] == d) ? 1.f : v;
    wout[e] = v;
  }
}

// ---------------- fused GNN2-layer1 (single row) + classifier (r7 verbatim) -------------
__global__ __launch_bounds__(128) void final_kernel(
    const float* __restrict__ hp, const float* __restrict__ ha,
    const int* __restrict__ idxPtr, const float* __restrict__ wpp,
    const int* __restrict__ cnt, const int* __restrict__ entries,
    const float* __restrict__ Wself, const float* __restrict__ Wpp,
    const float* __restrict__ Wap,
    const float* __restrict__ Wc, const float* __restrict__ bc,
    float* __restrict__ out)
{
  __shared__ float selfr[128], mpp[128], mapr[128], t[128];
  int tid = threadIdx.x;
  int idx = idxPtr[0];
  selfr[tid] = hp[(size_t)idx * 128 + tid];
  {
    int deg = cnt[idx];                                   // pp-dst bucket
    const int* ent = entries + (size_t)idx * BSLOT;
    float acc = 0.f;
    for (int k = 0; k < deg; ++k) {
      unsigned pl = (unsigned)ent[k];
      int s = (int)(pl >> 18);
      int e = (int)(pl & 0x3FFFFu);
      acc += wpp[e] * hp[(size_t)s * 128 + tid];
    }
    mpp[tid] = acc / fmaxf((float)deg, 1.0f);
  }
  {
    int deg = cnt[8192 + idx];                            // ap-dst bucket
    const int* ent = entries + (size_t)(8192 + idx) * BSLOT;
    float acc = 0.f;
    for (int k = 0; k < deg; ++k) {
      int s = ent[k];
      acc += ha[(size_t)s * 128 + tid];
    }
    mapr[tid] = acc / fmaxf((float)deg, 1.0f);
  }
  __syncthreads();
  float s = 0.f;
  for (int m = 0; m < 128; ++m) {
    s += selfr[m] * Wself[m * 128 + tid] + mpp[m] * Wpp[m * 128 + tid] +
         mapr[m] * Wap[m * 128 + tid];
  }
  t[tid] = fmaxf(s, 0.f);
  __syncthreads();
  if (tid < 5) {
    float y = bc[tid];
    for (int k = 0; k < 128; ++k) y += t[k] * Wc[k * 5 + tid];
    out[tid] = y;
  }
}

}  // namespace

extern "C" void kernel_launch(void* const* d_in, const int* in_sizes, int n_in,
                              void* d_out, int out_size, void* d_ws, size_t ws_size,
                              hipStream_t stream)
{
  (void)in_sizes; (void)n_in; (void)out_size; (void)ws_size;
  const float* x_p = (const float*)d_in[0];
  const float* x_a = (const float*)d_in[1];
  const int* ei_pp = (const int*)d_in[2];
  const int* ei_aa = (const int*)d_in[3];
  const int* ei_pa = (const int*)d_in[4];
  const int* ei_ap = (const int*)d_in[5];
  const int* idxPtr = (const int*)d_in[8];
  const float* Wself_p0 = (const float*)d_in[9];
  const float* Wself_p1 = (const float*)d_in[10];
  const float* Wself_a0 = (const float*)d_in[11];
  const float* Wself_a1 = (const float*)d_in[12];
  const float* Wpp0 = (const float*)d_in[13]; const float* Wpp1 = (const float*)d_in[14];
  const float* Waa0 = (const float*)d_in[15]; const float* Waa1 = (const float*)d_in[16];
  const float* Wpa0 = (const float*)d_in[17]; /* Wpa1 unused: author L1 dropped */
  const float* Wap0 = (const float*)d_in[19]; const float* Wap1 = (const float*)d_in[20];
  const float* Wep1_pp = (const float*)d_in[21]; const float* bep1_pp = (const float*)d_in[22];
  const float* Wep2_pp = (const float*)d_in[23]; const float* bep2_pp = (const float*)d_in[24];
  const float* Wep1_aa = (const float*)d_in[25]; const float* bep1_aa = (const float*)d_in[26];
  const float* Wep2_aa = (const float*)d_in[27]; const float* bep2_aa = (const float*)d_in[28];
  const float* Wc = (const float*)d_in[29]; const float* bc = (const float*)d_in[30];

  float* out = (float*)d_out;
  float* w_pp_out = out + 5;
  float* w_aa_out = out + 5 + EPPc;

  const int* src_pp = ei_pp;  const int* dst_pp = ei_pp + EPPc;
  const int* src_aa = ei_aa;  const int* dst_aa = ei_aa + EAAc;
  const int* src_pa = ei_pa;  const int* dst_pa = ei_pa + 131072;
  const int* src_ap = ei_ap;  const int* dst_ap = ei_ap + 131072;

  // ---- workspace layout (bump allocator; cnt first: it gets memset) ----
  char* p = (char*)d_ws;
  auto alloc = [&](size_t bytes) -> void* {
    void* r = (void*)p;
    p += (bytes + 255) & ~(size_t)255;
    return r;
  };
  int* cnt     = (int*)alloc(18432 * sizeof(int));
  int* entries = (int*)alloc((size_t)18432 * BSLOT * sizeof(int));  // 9.4 MB buckets
  float* Map  = (float*)alloc((size_t)NPn * Hh * sizeof(float));
  float* Mpa  = (float*)alloc((size_t)NAn * Hh * sizeof(float));
  float* h1p0 = (float*)alloc((size_t)NPn * Hh * sizeof(float));
  float* h1a0 = (float*)alloc((size_t)NAn * Hh * sizeof(float));
  float* h2p0 = (float*)alloc((size_t)NPn * Hh * sizeof(float));
  float* h2a0 = (float*)alloc((size_t)NAn * Hh * sizeof(float));
  float* P1pp = (float*)alloc((size_t)NPn * 256 * sizeof(float));
  float* P2pp = (float*)alloc((size_t)NPn * 256 * sizeof(float));
  float* P1aa = (float*)alloc((size_t)NAn * 256 * sizeof(float));
  float* P2aa = (float*)alloc((size_t)NAn * 256 * sizeof(float));

  // bucket cnt offsets
  const int CO_PPD = 0, CO_AAD = 4096, CO_PAD = 6144, CO_APD = 8192;

  hipMemsetAsync(cnt, 0, 18432 * sizeof(int), stream);
  scatter_kernel<<<2560, 256, 0, stream>>>(src_pp, dst_pp, src_aa, dst_aa,
                                           src_pa, dst_pa, src_ap, dst_ap,
                                           cnt, entries);

  // ---- K1: GNN1-L0 fused (agg+gemm) + agg-only Map/Mpa ----
  {
    FArgs fa{};
    fa.d[0] = {x_p, nullptr, CO_PPD, 18, nullptr,
               x_p, Wself_p0, Wpp0, nullptr, nullptr, h1p0, 1,
               nullptr, nullptr, nullptr};
    fa.d[1] = {x_a, nullptr, CO_AAD, 16, nullptr,
               x_a, Wself_a0, Waa0, nullptr, nullptr, h1a0, 1,
               nullptr, nullptr, nullptr};
    fa.d[2] = {x_a, nullptr, CO_APD, 0, Map,
               nullptr, nullptr, nullptr, nullptr, nullptr, nullptr, 0,
               nullptr, nullptr, nullptr};
    fa.d[3] = {x_p, nullptr, CO_PAD, 0, Mpa,
               nullptr, nullptr, nullptr, nullptr, nullptr, nullptr, 0,
               nullptr, nullptr, nullptr};
    fa.bstart[0] = 0; fa.bstart[1] = 512; fa.bstart[2] = 768;
    fa.bstart[3] = 1280; fa.bstart[4] = 1536; fa.nd = 4;
    fused_layer<<<1536, 256, 0, stream>>>(fa, cnt, entries);
  }

  // ---- K2: GNN1-L1 fused (agg+gemm) + P projections; h1p1 never materialized ----
  {
    FArgs fa{};
    fa.d[0] = {h1p0, nullptr, CO_PPD, 18, nullptr,
               h1p0, Wself_p1, Wpp1, nullptr, nullptr, nullptr, 1,
               Wep1_pp, P1pp, P2pp};
    fa.d[1] = {h1a0, nullptr, CO_AAD, 16, nullptr,
               h1a0, Wself_a1, Waa1, nullptr, nullptr, nullptr, 1,
               Wep1_aa, P1aa, P2aa};
    fa.bstart[0] = 0; fa.bstart[1] = 512; fa.bstart[2] = 768; fa.nd = 2;
    fused_layer<<<768, 256, 0, stream>>>(fa, cnt, entries);
  }

  // ---- JAX keys: key(42) -> split -> (kpp, kaa) (partitionable fold-in) ----
  uint32_t kpp0, kpp1, kaa0, kaa1;
  { uint32_t a0 = 0, a1 = 0; tf2x32(0u, 42u, a0, a1); kpp0 = a0; kpp1 = a1; }
  { uint32_t a0 = 0, a1 = 1; tf2x32(0u, 42u, a0, a1); kaa0 = a0; kaa1 = a1; }

  // ---- fused edge-pred + sparse coalesce + gumbel top-5 + w write (wave-per-row) ----
  row_topk<<<(NPn + NAn) / 4, 256, 0, stream>>>(P1pp, P2pp, bep1_pp, Wep2_pp, bep2_pp,
                                                P1aa, P2aa, bep1_aa, Wep2_aa, bep2_aa,
                                                cnt, entries, w_pp_out, w_aa_out,
                                                kpp0, kpp1, kaa0, kaa1);

  // ---- K3: GNN2-L0 fused (weighted agg + 3-part gemm; Map/Mpa from K1) ----
  {
    FArgs fa{};
    fa.d[0] = {x_p, w_pp_out, CO_PPD, 18, nullptr,
               x_p, Wself_p0, Wpp0, Map, Wap0, h2p0, 1,
               nullptr, nullptr, nullptr};
    fa.d[1] = {x_a, w_aa_out, CO_AAD, 16, nullptr,
               x_a, Wself_a0, Waa0, Mpa, Wpa0, h2a0, 1,
               nullptr, nullptr, nullptr};
    fa.bstart[0] = 0; fa.bstart[1] = 512; fa.bstart[2] = 768; fa.nd = 2;
    fused_layer<<<768, 256, 0, stream>>>(fa, cnt, entries);
  }

  // ---- GNN2 layer 1 only needed at one paper row -> fused with classifier ----
  final_kernel<<<1, 128, 0, stream>>>(h2p0, h2a0, idxPtr, w_pp_out,
                                      cnt, entries,
                                      Wself_p1, Wpp1, Wap1, Wc, bc, out);
}

// Round 10
// 315.207 us; speedup vs baseline: 1.0523x; 1.0523x over previous
//
#include <hip/hip_runtime.h>
#include <stdint.h>

// ---------------------------------------------------------------------------
// MultiGraph hetero-GNN + gumbel-top-k edge pruning, fp32 throughout.
// Round 17 (from r13 @ 316.0us best; r16 wave-column partition regressed via
// self-inflicted 8-way av-read bank conflict -- conflicts 2.36M->4.72M):
//  fused_layer GEMM: wave-column partition (m=lane>>3, colq=wv*8+(lane&7))
//  RETAINED, but A-tiles padded to [8][132] (132 % 32 == 4 -> row m starts
//  at bank offset 4m; the 8 m-group reads at a fixed column hit 8 disjoint
//  bank quads = all 32 banks, conflict-free; 132%4==0 keeps float4 align).
//  Per chunk per wave: w-reads 128B distinct (8-way broadcast) AND av-reads
//  conflict-free -> ~3x less LDS pipe time than r13's full-row w-reads.
//  FMA chains keep exact (part, chunk, k)-ascending order -> bit-exact.
//  Agg r13 / W-prefetch r12 / row_topk r13 / scatter / final verbatim.
// PRNG: JAX threefry2x32, partitionable path (verified absmax=0.0 r1-r16).
// ---------------------------------------------------------------------------

namespace {

constexpr int NPn = 4096;
constexpr int NAn = 2048;
constexpr int Hh  = 128;
constexpr int EPPc = 131072;
constexpr int EAAc = 65536;
constexpr int KSEL = 5;
constexpr int BSLOT = 128;   // bucket capacity per node (deg<128: Poisson-32, e^-85 tail)
constexpr int APAD = 132;    // padded A-tile row stride (bank offset 4/row)

// bucket segments (cnt index = co + node; entries base = (co+node)*128):
// 0: pp-dst (4096)   4096: aa-dst (2048)   6144: pa-dst (2048)
// 8192: ap-dst (4096) 12288: pp-src (4096) 16384: aa-src (2048)
// payloads: pp: (other<<18)|e  aa: (other<<16)|e  pa/ap: src only

__host__ __device__ static inline void tf2x32(uint32_t k0, uint32_t k1,
                                              uint32_t& x0, uint32_t& x1) {
  uint32_t ks2 = k0 ^ k1 ^ 0x1BD11BDAu;
  x0 += k0; x1 += k1;
#define TF_R(r) { x0 += x1; x1 = (x1 << (r)) | (x1 >> (32 - (r))); x1 ^= x0; }
  TF_R(13) TF_R(15) TF_R(26) TF_R(6)
  x0 += k1;  x1 += ks2 + 1u;
  TF_R(17) TF_R(29) TF_R(16) TF_R(24)
  x0 += ks2; x1 += k0 + 2u;
  TF_R(13) TF_R(15) TF_R(26) TF_R(6)
  x0 += k0;  x1 += k1 + 3u;
  TF_R(17) TF_R(29) TF_R(16) TF_R(24)
  x0 += k1;  x1 += ks2 + 4u;
  TF_R(13) TF_R(15) TF_R(26) TF_R(6)
  x0 += ks2; x1 += k0 + 5u;
#undef TF_R
}

// ---------------- bucket scatter (r7 verbatim) ----------------
__global__ __launch_bounds__(256) void scatter_kernel(
    const int* src_pp, const int* dst_pp, const int* src_aa, const int* dst_aa,
    const int* src_pa, const int* dst_pa, const int* src_ap, const int* dst_ap,
    int* cnt, int* entries)
{
  int i = blockIdx.x * 256 + threadIdx.x;
  int key, pl;
  if (i < 131072) {                       // pp by dst
    int e = i;
    key = 0 + dst_pp[e]; pl = (src_pp[e] << 18) | e;
  } else if (i < 196608) {                // aa by dst
    int e = i - 131072;
    key = 4096 + dst_aa[e]; pl = (src_aa[e] << 16) | e;
  } else if (i < 327680) {                // pa by dst (payload = src paper)
    int e = i - 196608;
    key = 6144 + dst_pa[e]; pl = src_pa[e];
  } else if (i < 458752) {                // ap by dst (payload = src author)
    int e = i - 327680;
    key = 8192 + dst_ap[e]; pl = src_ap[e];
  } else if (i < 589824) {                // pp by src (payload = (dst<<18)|e)
    int e = i - 458752;
    key = 12288 + src_pp[e]; pl = (dst_pp[e] << 18) | e;
  } else if (i < 655360) {                // aa by src
    int e = i - 589824;
    key = 16384 + src_aa[e]; pl = (dst_aa[e] << 16) | e;
  } else return;
  int pos = atomicAdd(&cnt[key], 1);
  if (pos < BSLOT) entries[key * BSLOT + pos] = pl;
}

// ---------------- fused agg + GEMM (+ optional P projections) --------------------------
// r17: 8 nodes per block. Agg: r13 half-wave-per-node 8-unroll. GEMM: Ws
// chunks with register prefetch (r12); wave-column consumer (m=lane>>3,
// colq=wv*8+(lane&7)) on [8][132]-padded A-tiles -> both w and av reads
// conflict-free. P stage: r9 body on padded Xs.
struct FDesc {
  const float* gsrc; const float* wArr; int cntOff; int shift;
  float* Mout;                                  // agg-only output (when W0 == null)
  const float* Aself; const float* W0; const float* W1;
  const float* A2;  const float* W2;            // optional part 2
  float* C; int relu;                           // C may be null (P-only)
  const float* WP; float* P1; float* P2;        // optional P stage
};
struct FArgs { FDesc d[4]; int bstart[5]; int nd; };

__global__ __launch_bounds__(256) void fused_layer(FArgs fa, const int* __restrict__ cnt,
                                                   const int* __restrict__ entries)
{
  __shared__ __align__(16) float Xs[8][APAD];
  __shared__ __align__(16) float Ms[8][APAD];
  __shared__ __align__(16) float Zs[8][APAD];
  __shared__ __align__(16) float Ws[32][128];
  int blk = blockIdx.x, tid = threadIdx.x;
  int di = 0;
  while (di < fa.nd - 1 && blk >= fa.bstart[di + 1]) ++di;
  FDesc D = fa.d[di];
  int node0 = (blk - fa.bstart[di]) * 8;
  // ---- agg phase (r13: half-wave per node, 8-unrolled) ----
  {
    int hw = tid >> 5;
    int node = node0 + hw;
    int fl = (tid & 31) << 2;
    int deg = cnt[D.cntOff + node];
    const int* ent = entries + (size_t)(D.cntOff + node) * BSLOT;
    const float* h = D.gsrc;
    int sh = D.shift;
    float ax = 0.f, ay = 0.f, az = 0.f, aw = 0.f;
    if (D.wArr) {
      unsigned mask = (1u << sh) - 1u;
      int k = 0;
      for (; k + 3 < deg; k += 4) {
        unsigned p0 = (unsigned)ent[k], p1 = (unsigned)ent[k + 1];
        unsigned p2 = (unsigned)ent[k + 2], p3 = (unsigned)ent[k + 3];
        float w0 = D.wArr[p0 & mask], w1 = D.wArr[p1 & mask];
        float w2v = D.wArr[p2 & mask], w3 = D.wArr[p3 & mask];
        float4 v0, v1, v2, v3;
        if (w0 != 0.f) v0 = *(const float4*)&h[(size_t)(p0 >> sh) * Hh + fl];
        if (w1 != 0.f) v1 = *(const float4*)&h[(size_t)(p1 >> sh) * Hh + fl];
        if (w2v != 0.f) v2 = *(const float4*)&h[(size_t)(p2 >> sh) * Hh + fl];
        if (w3 != 0.f) v3 = *(const float4*)&h[(size_t)(p3 >> sh) * Hh + fl];
        if (w0 != 0.f) { ax += v0.x; ay += v0.y; az += v0.z; aw += v0.w; }
        if (w1 != 0.f) { ax += v1.x; ay += v1.y; az += v1.z; aw += v1.w; }
        if (w2v != 0.f) { ax += v2.x; ay += v2.y; az += v2.z; aw += v2.w; }
        if (w3 != 0.f) { ax += v3.x; ay += v3.y; az += v3.z; aw += v3.w; }
      }
      for (; k < deg; ++k) {
        unsigned pl = (unsigned)ent[k];
        float wt = D.wArr[pl & mask];
        if (wt != 0.f) {
          float4 v = *(const float4*)&h[(size_t)(pl >> sh) * Hh + fl];
          ax += v.x; ay += v.y; az += v.z; aw += v.w;
        }
      }
    } else {
      int k = 0;
      for (; k + 7 < deg; k += 8) {
        unsigned p0 = (unsigned)ent[k],     p1 = (unsigned)ent[k + 1];
        unsigned p2 = (unsigned)ent[k + 2], p3 = (unsigned)ent[k + 3];
        unsigned p4 = (unsigned)ent[k + 4], p5 = (unsigned)ent[k + 5];
        unsigned p6 = (unsigned)ent[k + 6], p7 = (unsigned)ent[k + 7];
        float4 v0 = *(const float4*)&h[(size_t)(p0 >> sh) * Hh + fl];
        float4 v1 = *(const float4*)&h[(size_t)(p1 >> sh) * Hh + fl];
        float4 v2 = *(const float4*)&h[(size_t)(p2 >> sh) * Hh + fl];
        float4 v3 = *(const float4*)&h[(size_t)(p3 >> sh) * Hh + fl];
        float4 v4 = *(const float4*)&h[(size_t)(p4 >> sh) * Hh + fl];
        float4 v5 = *(const float4*)&h[(size_t)(p5 >> sh) * Hh + fl];
        float4 v6 = *(const float4*)&h[(size_t)(p6 >> sh) * Hh + fl];
        float4 v7 = *(const float4*)&h[(size_t)(p7 >> sh) * Hh + fl];
        ax += v0.x; ay += v0.y; az += v0.z; aw += v0.w;
        ax += v1.x; ay += v1.y; az += v1.z; aw += v1.w;
        ax += v2.x; ay += v2.y; az += v2.z; aw += v2.w;
        ax += v3.x; ay += v3.y; az += v3.z; aw += v3.w;
        ax += v4.x; ay += v4.y; az += v4.z; aw += v4.w;
        ax += v5.x; ay += v5.y; az += v5.z; aw += v5.w;
        ax += v6.x; ay += v6.y; az += v6.z; aw += v6.w;
        ax += v7.x; ay += v7.y; az += v7.z; aw += v7.w;
      }
      for (; k < deg; ++k) {
        unsigned pl = (unsigned)ent[k];
        float4 v = *(const float4*)&h[(size_t)(pl >> sh) * Hh + fl];
        ax += v.x; ay += v.y; az += v.z; aw += v.w;
      }
    }
    float cd = fmaxf((float)deg, 1.0f);
    float4 o; o.x = ax / cd; o.y = ay / cd; o.z = az / cd; o.w = aw / cd;
    if (D.W0 == nullptr) {
      *(float4*)&D.Mout[(size_t)node * Hh + fl] = o;
    } else {
      *(float4*)&Ms[hw][fl] = o;
    }
  }
  if (D.W0 == nullptr) return;   // agg-only block (uniform per block)
  // ---- stage self rows (and part-2 rows): contiguous, coalesced ----
  {
    int rm = tid >> 5, cq = (tid & 31) << 2;
    *(float4*)&Xs[rm][cq] = *(const float4*)&D.Aself[(size_t)(node0 + rm) * 128 + cq];
    if (D.A2)
      *(float4*)&Zs[rm][cq] = *(const float4*)&D.A2[(size_t)(node0 + rm) * 128 + cq];
  }
  // ---- GEMM: wave-column consumer on padded A-tiles. Thread -> (m=lane>>3,
  // colq=wv*8+(lane&7)); 4 outputs C[m][colq*4..+3]. Both Ws reads (8-way
  // broadcast, 128B/k distinct) and av reads (8 disjoint bank quads) are
  // conflict-free. Chain: part-major, chunk, k ascending (== r13 -> bit-exact).
  int lane = tid & 63;
  int m = lane >> 3;
  int colq = ((tid >> 6) << 3) | (lane & 7);
  int r = tid >> 3, f = (tid & 7) << 4;
  float4 accv = {0.f, 0.f, 0.f, 0.f};
  int parts = D.A2 ? 3 : 2;
  int T = parts * 4;
  float4 g0, g1, g2, g3;
  {
    const float* srcp = &D.W0[(size_t)r * 128 + f];       // chunk 0: rows 0..31
    g0 = *(const float4*)&srcp[0];
    g1 = *(const float4*)&srcp[4];
    g2 = *(const float4*)&srcp[8];
    g3 = *(const float4*)&srcp[12];
  }
  for (int t = 0; t < T; ++t) {
    __syncthreads();                     // chunk t-1 consumed / agg+stage visible
    *(float4*)&Ws[r][f]      = g0;
    *(float4*)&Ws[r][f + 4]  = g1;
    *(float4*)&Ws[r][f + 8]  = g2;
    *(float4*)&Ws[r][f + 12] = g3;
    if (t + 1 < T) {                     // issue chunk t+1 loads; land under compute
      int p2 = (t + 1) >> 2, ci = (t + 1) & 3;
      const float* Wn = (p2 == 0) ? D.W0 : (p2 == 1) ? D.W1 : D.W2;
      const float* srcp = &Wn[(size_t)(ci * 32 + r) * 128 + f];
      g0 = *(const float4*)&srcp[0];
      g1 = *(const float4*)&srcp[4];
      g2 = *(const float4*)&srcp[8];
      g3 = *(const float4*)&srcp[12];
    }
    __syncthreads();                     // Ws chunk t visible
    int p = t >> 2, c = t & 3;
#define KCHUNK(AR)                                              \
    _Pragma("unroll")                                           \
    for (int k4 = 0; k4 < 32; k4 += 4) {                        \
      float4 av = *(const float4*)&AR[m][c * 32 + k4];          \
      float4 w0 = *(const float4*)&Ws[k4 + 0][colq << 2];       \
      float4 w1 = *(const float4*)&Ws[k4 + 1][colq << 2];       \
      float4 w2v = *(const float4*)&Ws[k4 + 2][colq << 2];      \
      float4 w3 = *(const float4*)&Ws[k4 + 3][colq << 2];       \
      accv.x += av.x * w0.x; accv.y += av.x * w0.y;             \
      accv.z += av.x * w0.z; accv.w += av.x * w0.w;             \
      accv.x += av.y * w1.x; accv.y += av.y * w1.y;             \
      accv.z += av.y * w1.z; accv.w += av.y * w1.w;             \
      accv.x += av.z * w2v.x; accv.y += av.z * w2v.y;           \
      accv.z += av.z * w2v.z; accv.w += av.z * w2v.w;           \
      accv.x += av.w * w3.x; accv.y += av.w * w3.y;             \
      accv.z += av.w * w3.z; accv.w += av.w * w3.w;             \
    }
    if (p == 0) { KCHUNK(Xs) } else if (p == 1) { KCHUNK(Ms) } else { KCHUNK(Zs) }
#undef KCHUNK
  }
  if (D.relu) {
    accv.x = fmaxf(accv.x, 0.f); accv.y = fmaxf(accv.y, 0.f);
    accv.z = fmaxf(accv.z, 0.f); accv.w = fmaxf(accv.w, 0.f);
  }
  if (D.C)
    *(float4*)&D.C[(size_t)(node0 + m) * 128 + (colq << 2)] = accv;
  if (D.WP == nullptr) return;
  // ---- P stage: h rows -> LDS (reuse Xs), then P1/P2 = h @ WP halves.
  // r9 body on padded Xs; k ascending -> bit-exact.
  __syncthreads();
  *(float4*)&Xs[m][colq << 2] = accv;
  __syncthreads();
  {
    int half = tid >> 7;                 // 0 -> P1 (WP rows 0..127), 1 -> P2 (rows 128..255)
    int rg = (tid >> 6) & 1;             // row quad: rows rg*4 .. rg*4+3
    int c0 = (tid & 63) << 2;            // 4 cols
    const float* Wb = D.WP + ((size_t)(half ? 128 : 0)) * 256 + c0;
    float4 acc0 = {0,0,0,0}, acc1 = {0,0,0,0}, acc2 = {0,0,0,0}, acc3 = {0,0,0,0};
    for (int k = 0; k < 128; k += 2) {
      float4 w0 = *(const float4*)&Wb[(size_t)k * 256];
      float4 w1 = *(const float4*)&Wb[(size_t)(k + 1) * 256];
      float2 a0 = *(const float2*)&Xs[rg * 4 + 0][k];
      float2 a1 = *(const float2*)&Xs[rg * 4 + 1][k];
      float2 a2 = *(const float2*)&Xs[rg * 4 + 2][k];
      float2 a3 = *(const float2*)&Xs[rg * 4 + 3][k];
      acc0.x += a0.x * w0.x; acc0.y += a0.x * w0.y; acc0.z += a0.x * w0.z; acc0.w += a0.x * w0.w;
      acc0.x += a0.y * w1.x; acc0.y += a0.y * w1.y; acc0.z += a0.y * w1.z; acc0.w += a0.y * w1.w;
      acc1.x += a1.x * w0.x; acc1.y += a1.x * w0.y; acc1.z += a1.x * w0.z; acc1.w += a1.x * w0.w;
      acc1.x += a1.y * w1.x; acc1.y += a1.y * w1.y; acc1.z += a1.y * w1.z; acc1.w += a1.y * w1.w;
      acc2.x += a2.x * w0.x; acc2.y += a2.x * w0.y; acc2.z += a2.x * w0.z; acc2.w += a2.x * w0.w;
      acc2.x += a2.y * w1.x; acc2.y += a2.y * w1.y; acc2.z += a2.y * w1.z; acc2.w += a2.y * w1.w;
      acc3.x += a3.x * w0.x; acc3.y += a3.x * w0.y; acc3.z += a3.x * w0.z; acc3.w += a3.x * w0.w;
      acc3.x += a3.y * w1.x; acc3.y += a3.y * w1.y; acc3.z += a3.y * w1.z; acc3.w += a3.y * w1.w;
    }
    float* Pout = half ? D.P2 : D.P1;
    *(float4*)&Pout[(size_t)(node0 + rg * 4 + 0) * 256 + c0] = acc0;
    *(float4*)&Pout[(size_t)(node0 + rg * 4 + 1) * 256 + c0] = acc1;
    *(float4*)&Pout[(size_t)(node0 + rg * 4 + 2) * 256 + c0] = acc2;
    *(float4*)&Pout[(size_t)(node0 + rg * 4 + 3) * 256 + c0] = acc3;
  }
}

// ---------------- fused edge-MLP + sparse coalesce + masked gumbel top-5 ----------------
// r13 verbatim: coalesce loop reads dS/pS via LDS broadcast; deg<=64 fast
// path. MLP 8-edge unroll / reduce tree / sel5 protocol verbatim.
__global__ __launch_bounds__(256) void row_topk(
    const float* __restrict__ P1pp, const float* __restrict__ P2pp,
    const float* __restrict__ b1pp, const float* __restrict__ W2pp,
    const float* __restrict__ b2pp,
    const float* __restrict__ P1aa, const float* __restrict__ P2aa,
    const float* __restrict__ b1aa, const float* __restrict__ W2aa,
    const float* __restrict__ b2aa,
    const int* __restrict__ cnt, const int* __restrict__ entries,
    float* __restrict__ w_pp, float* __restrict__ w_aa,
    uint32_t kpp0, uint32_t kpp1, uint32_t kaa0, uint32_t kaa1)
{
  __shared__ int   dS[4][128];
  __shared__ float pS[4][128];
  __shared__ int   sel5[4][KSEL];
  int blk = blockIdx.x, tid = threadIdx.x;
  int lane = tid & 63, wv = tid >> 6;
  int row, Ncols, shift;
  int co; unsigned mask;
  const float* P1; const float* P2; const float* b1; const float* W2; const float* b2;
  float* wout; uint32_t k0, k1;
  if (blk < NPn / 4) {
    row = blk * 4 + wv; Ncols = NPn; shift = 18; mask = 0x3FFFFu; co = 12288;
    P1 = P1pp; P2 = P2pp; b1 = b1pp; W2 = W2pp; b2 = b2pp;
    wout = w_pp; k0 = kpp0; k1 = kpp1;
  } else {
    row = (blk - NPn / 4) * 4 + wv; Ncols = NAn; shift = 16; mask = 0xFFFFu; co = 16384;
    P1 = P1aa; P2 = P2aa; b1 = b1aa; W2 = W2aa; b2 = b2aa;
    wout = w_aa; k0 = kaa0; k1 = kaa1;
  }
  const int* ent = entries + (size_t)(co + row) * BSLOT;
  int deg = cnt[co + row];
  int j = lane << 2;
  // per-lane register staging (each lane only ever touches its j..j+3 slice)
  float4 p1v = *(const float4*)&P1[(size_t)row * 256 + j];
  float4 b1v = *(const float4*)&b1[j];
  float wa = W2[(j + 0) * 2], wb = W2[(j + 1) * 2];
  float wc = W2[(j + 2) * 2], wd = W2[(j + 3) * 2];
  float bias2 = b2[0];
  float pa = p1v.x, pb = p1v.y, pc = p1v.z, pd = p1v.w;
  float ba = b1v.x, bb = b1v.y, bc_ = b1v.z, bd = b1v.w;
#define SCORE(q) (fmaxf(pa + q.x + ba, 0.f) * wa + fmaxf(pb + q.y + bb, 0.f) * wb + \
                  fmaxf(pc + q.z + bc_, 0.f) * wc + fmaxf(pd + q.w + bd, 0.f) * wd)
  for (int k = 0; k < deg; k += 8) {
    int n = deg - k; if (n > 8) n = 8;
    unsigned pl0 = (unsigned)ent[k];
    unsigned pl1 = (n > 1) ? (unsigned)ent[k + 1] : pl0;
    unsigned pl2 = (n > 2) ? (unsigned)ent[k + 2] : pl0;
    unsigned pl3 = (n > 3) ? (unsigned)ent[k + 3] : pl0;
    unsigned pl4 = (n > 4) ? (unsigned)ent[k + 4] : pl0;
    unsigned pl5 = (n > 5) ? (unsigned)ent[k + 5] : pl0;
    unsigned pl6 = (n > 6) ? (unsigned)ent[k + 6] : pl0;
    unsigned pl7 = (n > 7) ? (unsigned)ent[k + 7] : pl0;
    int d0 = (int)(pl0 >> shift), d1 = (int)(pl1 >> shift);
    int d2 = (int)(pl2 >> shift), d3 = (int)(pl3 >> shift);
    int d4 = (int)(pl4 >> shift), d5 = (int)(pl5 >> shift);
    int d6 = (int)(pl6 >> shift), d7 = (int)(pl7 >> shift);
    float4 q0 = *(const float4*)&P2[(size_t)d0 * 256 + j];
    float4 q1 = *(const float4*)&P2[(size_t)d1 * 256 + j];
    float4 q2 = *(const float4*)&P2[(size_t)d2 * 256 + j];
    float4 q3 = *(const float4*)&P2[(size_t)d3 * 256 + j];
    float4 q4 = *(const float4*)&P2[(size_t)d4 * 256 + j];
    float4 q5 = *(const float4*)&P2[(size_t)d5 * 256 + j];
    float4 q6 = *(const float4*)&P2[(size_t)d6 * 256 + j];
    float4 q7 = *(const float4*)&P2[(size_t)d7 * 256 + j];
    float s0 = SCORE(q0), s1 = SCORE(q1), s2 = SCORE(q2), s3 = SCORE(q3);
    float s4 = SCORE(q4), s5 = SCORE(q5), s6 = SCORE(q6), s7 = SCORE(q7);
    for (int off = 32; off; off >>= 1) {
      s0 += __shfl_down(s0, off);
      s1 += __shfl_down(s1, off);
      s2 += __shfl_down(s2, off);
      s3 += __shfl_down(s3, off);
      s4 += __shfl_down(s4, off);
      s5 += __shfl_down(s5, off);
      s6 += __shfl_down(s6, off);
      s7 += __shfl_down(s7, off);
    }
    if (lane == 0) {
      dS[wv][k] = d0; pS[wv][k] = s0 + bias2;
      if (n > 1) { dS[wv][k + 1] = d1; pS[wv][k + 1] = s1 + bias2; }
      if (n > 2) { dS[wv][k + 2] = d2; pS[wv][k + 2] = s2 + bias2; }
      if (n > 3) { dS[wv][k + 3] = d3; pS[wv][k + 3] = s3 + bias2; }
      if (n > 4) { dS[wv][k + 4] = d4; pS[wv][k + 4] = s4 + bias2; }
      if (n > 5) { dS[wv][k + 5] = d5; pS[wv][k + 5] = s5 + bias2; }
      if (n > 6) { dS[wv][k + 6] = d6; pS[wv][k + 6] = s6 + bias2; }
      if (n > 7) { dS[wv][k + 7] = d7; pS[wv][k + 7] = s7 + bias2; }
    }
  }
#undef SCORE
  __syncthreads();
  if (deg > 0) {
    int   e0 = (lane < deg) ? dS[wv][lane] : -1;
    bool  two = (deg > 64);
    int   e1 = -1;
    if (two && 64 + lane < deg) e1 = dS[wv][64 + lane];
    float a0 = 0.f, a1 = 0.f;
    bool lead0 = (e0 >= 0), lead1 = (e1 >= 0);
    // LDS-broadcast coalesce (values/order identical to the shfl version:
    // pS[wv][j2] == __shfl(q0v/q1v, ...), j2 ascending -> bit-exact).
    if (!two) {
#pragma unroll 4
      for (int j2 = 0; j2 < deg; ++j2) {
        int bj = dS[wv][j2]; float bp = pS[wv][j2];
        if (bj == e0) { a0 += bp; if (j2 < lane) lead0 = false; }   // e0==-1 never matches
      }
    } else {
#pragma unroll 2
      for (int j2 = 0; j2 < deg; ++j2) {
        int bj = dS[wv][j2]; float bp = pS[wv][j2];
        if (e0 >= 0 && bj == e0) { a0 += bp; if (j2 < lane) lead0 = false; }
        if (e1 >= 0 && bj == e1) { a1 += bp; if (j2 < 64 + lane) lead1 = false; }
      }
    }
    uint32_t rowbase = (uint32_t)row * (uint32_t)Ncols;
    float y0 = -1e9f, y1 = -1e9f;
    bool c0 = lead0 && (a0 > 0.f);
    if (c0) {
      uint32_t x0 = 0u, x1 = rowbase + (uint32_t)e0;
      tf2x32(k0, k1, x0, x1);
      uint32_t bits = x0 ^ x1;
      float fv = __uint_as_float((bits >> 9) | 0x3f800000u) - 1.0f;
      float u = fmaxf(1e-10f, fv + 1e-10f);
      y0 = a0 + (-logf(-logf(u)));
    }
    bool c1 = lead1 && (a1 > 0.f);
    if (c1) {
      uint32_t x0 = 0u, x1 = rowbase + (uint32_t)e1;
      tf2x32(k0, k1, x0, x1);
      uint32_t bits = x0 ^ x1;
      float fv = __uint_as_float((bits >> 9) | 0x3f800000u) - 1.0f;
      float u = fmaxf(1e-10f, fv + 1e-10f);
      y1 = a1 + (-logf(-logf(u)));
    }
    int cnt2 = __popcll(__ballot(c0)) + __popcll(__ballot(c1));
    int nsel = cnt2 < KSEL ? cnt2 : KSEL;
    for (int it = 0; it < nsel; ++it) {
      float best; int bc;
      if (y1 > y0 || (y1 == y0 && (unsigned)e1 < (unsigned)e0)) { best = y1; bc = e1; }
      else { best = y0; bc = e0; }
      for (int mm = 32; mm; mm >>= 1) {
        float ov = __shfl_xor(best, mm); int oc = __shfl_xor(bc, mm);
        if (ov > best || (ov == best && (unsigned)oc < (unsigned)bc)) { best = ov; bc = oc; }
      }
      if (lane == 0) sel5[wv][it] = bc;
      if (e0 == bc) y0 = -3.0e38f;
      if (e1 == bc) y1 = -3.0e38f;
    }
    if (nsel < KSEL && lane == 0) {
      int c = 0;
      for (int it = nsel; it < KSEL; ++it) {
        for (;;) {
          bool used = false;
          for (int q = 0; q < it; ++q) used |= (sel5[wv][q] == c);
          if (!used) break;
          ++c;
        }
        sel5[wv][it] = c++;
      }
    }
  }
  __syncthreads();
  for (int k = lane; k < deg; k += 64) {
    unsigned pl = (unsigned)ent[k];
    int d = (int)(pl >> shift);
    int e = (int)(pl & mask);
    float v = 0.f;
#pragma unroll
    for (int q = 0; q < KSEL; ++q) v = (sel5[wv][q] == d) ? 1.f : v;
    wout[e] = v;
  }
}

// ---------------- fused GNN2-layer1 (single row) + classifier (r7 verbatim) -------------
__global__ __launch_bounds__(128) void final_kernel(
    const float* __restrict__ hp, const float* __restrict__ ha,
    const int* __restrict__ idxPtr, const float* __restrict__ wpp,
    const int* __restrict__ cnt, const int* __restrict__ entries,
    const float* __restrict__ Wself, const float* __restrict__ Wpp,
    const float* __restrict__ Wap,
    const float* __restrict__ Wc, const float* __restrict__ bc,
    float* __restrict__ out)
{
  __shared__ float selfr[128], mpp[128], mapr[128], t[128];
  int tid = threadIdx.x;
  int idx = idxPtr[0];
  selfr[tid] = hp[(size_t)idx * 128 + tid];
  {
    int deg = cnt[idx];                                   // pp-dst bucket
    const int* ent = entries + (size_t)idx * BSLOT;
    float acc = 0.f;
    for (int k = 0; k < deg; ++k) {
      unsigned pl = (unsigned)ent[k];
      int s = (int)(pl >> 18);
      int e = (int)(pl & 0x3FFFFu);
      acc += wpp[e] * hp[(size_t)s * 128 + tid];
    }
    mpp[tid] = acc / fmaxf((float)deg, 1.0f);
  }
  {
    int deg = cnt[8192 + idx];                            // ap-dst bucket
    const int* ent = entries + (size_t)(8192 + idx) * BSLOT;
    float acc = 0.f;
    for (int k = 0; k < deg; ++k) {
      int s = ent[k];
      acc += ha[(size_t)s * 128 + tid];
    }
    mapr[tid] = acc / fmaxf((float)deg, 1.0f);
  }
  __syncthreads();
  float s = 0.f;
  for (int m = 0; m < 128; ++m) {
    s += selfr[m] * Wself[m * 128 + tid] + mpp[m] * Wpp[m * 128 + tid] +
         mapr[m] * Wap[m * 128 + tid];
  }
  t[tid] = fmaxf(s, 0.f);
  __syncthreads();
  if (tid < 5) {
    float y = bc[tid];
    for (int k = 0; k < 128; ++k) y += t[k] * Wc[k * 5 + tid];
    out[tid] = y;
  }
}

}  // namespace

extern "C" void kernel_launch(void* const* d_in, const int* in_sizes, int n_in,
                              void* d_out, int out_size, void* d_ws, size_t ws_size,
                              hipStream_t stream)
{
  (void)in_sizes; (void)n_in; (void)out_size; (void)ws_size;
  const float* x_p = (const float*)d_in[0];
  const float* x_a = (const float*)d_in[1];
  const int* ei_pp = (const int*)d_in[2];
  const int* ei_aa = (const int*)d_in[3];
  const int* ei_pa = (const int*)d_in[4];
  const int* ei_ap = (const int*)d_in[5];
  const int* idxPtr = (const int*)d_in[8];
  const float* Wself_p0 = (const float*)d_in[9];
  const float* Wself_p1 = (const float*)d_in[10];
  const float* Wself_a0 = (const float*)d_in[11];
  const float* Wself_a1 = (const float*)d_in[12];
  const float* Wpp0 = (const float*)d_in[13]; const float* Wpp1 = (const float*)d_in[14];
  const float* Waa0 = (const float*)d_in[15]; const float* Waa1 = (const float*)d_in[16];
  const float* Wpa0 = (const float*)d_in[17]; /* Wpa1 unused: author L1 dropped */
  const float* Wap0 = (const float*)d_in[19]; const float* Wap1 = (const float*)d_in[20];
  const float* Wep1_pp = (const float*)d_in[21]; const float* bep1_pp = (const float*)d_in[22];
  const float* Wep2_pp = (const float*)d_in[23]; const float* bep2_pp = (const float*)d_in[24];
  const float* Wep1_aa = (const float*)d_in[25]; const float* bep1_aa = (const float*)d_in[26];
  const float* Wep2_aa = (const float*)d_in[27]; const float* bep2_aa = (const float*)d_in[28];
  const float* Wc = (const float*)d_in[29]; const float* bc = (const float*)d_in[30];

  float* out = (float*)d_out;
  float* w_pp_out = out + 5;
  float* w_aa_out = out + 5 + EPPc;

  const int* src_pp = ei_pp;  const int* dst_pp = ei_pp + EPPc;
  const int* src_aa = ei_aa;  const int* dst_aa = ei_aa + EAAc;
  const int* src_pa = ei_pa;  const int* dst_pa = ei_pa + 131072;
  const int* src_ap = ei_ap;  const int* dst_ap = ei_ap + 131072;

  // ---- workspace layout (bump allocator; cnt first: it gets memset) ----
  char* p = (char*)d_ws;
  auto alloc = [&](size_t bytes) -> void* {
    void* r = (void*)p;
    p += (bytes + 255) & ~(size_t)255;
    return r;
  };
  int* cnt     = (int*)alloc(18432 * sizeof(int));
  int* entries = (int*)alloc((size_t)18432 * BSLOT * sizeof(int));  // 9.4 MB buckets
  float* Map  = (float*)alloc((size_t)NPn * Hh * sizeof(float));
  float* Mpa  = (float*)alloc((size_t)NAn * Hh * sizeof(float));
  float* h1p0 = (float*)alloc((size_t)NPn * Hh * sizeof(float));
  float* h1a0 = (float*)alloc((size_t)NAn * Hh * sizeof(float));
  float* h2p0 = (float*)alloc((size_t)NPn * Hh * sizeof(float));
  float* h2a0 = (float*)alloc((size_t)NAn * Hh * sizeof(float));
  float* P1pp = (float*)alloc((size_t)NPn * 256 * sizeof(float));
  float* P2pp = (float*)alloc((size_t)NPn * 256 * sizeof(float));
  float* P1aa = (float*)alloc((size_t)NAn * 256 * sizeof(float));
  float* P2aa = (float*)alloc((size_t)NAn * 256 * sizeof(float));

  // bucket cnt offsets
  const int CO_PPD = 0, CO_AAD = 4096, CO_PAD = 6144, CO_APD = 8192;

  hipMemsetAsync(cnt, 0, 18432 * sizeof(int), stream);
  scatter_kernel<<<2560, 256, 0, stream>>>(src_pp, dst_pp, src_aa, dst_aa,
                                           src_pa, dst_pa, src_ap, dst_ap,
                                           cnt, entries);

  // ---- K1: GNN1-L0 fused (agg+gemm) + agg-only Map/Mpa ----
  {
    FArgs fa{};
    fa.d[0] = {x_p, nullptr, CO_PPD, 18, nullptr,
               x_p, Wself_p0, Wpp0, nullptr, nullptr, h1p0, 1,
               nullptr, nullptr, nullptr};
    fa.d[1] = {x_a, nullptr, CO_AAD, 16, nullptr,
               x_a, Wself_a0, Waa0, nullptr, nullptr, h1a0, 1,
               nullptr, nullptr, nullptr};
    fa.d[2] = {x_a, nullptr, CO_APD, 0, Map,
               nullptr, nullptr, nullptr, nullptr, nullptr, nullptr, 0,
               nullptr, nullptr, nullptr};
    fa.d[3] = {x_p, nullptr, CO_PAD, 0, Mpa,
               nullptr, nullptr, nullptr, nullptr, nullptr, nullptr, 0,
               nullptr, nullptr, nullptr};
    fa.bstart[0] = 0; fa.bstart[1] = 512; fa.bstart[2] = 768;
    fa.bstart[3] = 1280; fa.bstart[4] = 1536; fa.nd = 4;
    fused_layer<<<1536, 256, 0, stream>>>(fa, cnt, entries);
  }

  // ---- K2: GNN1-L1 fused (agg+gemm) + P projections; h1p1 never materialized ----
  {
    FArgs fa{};
    fa.d[0] = {h1p0, nullptr, CO_PPD, 18, nullptr,
               h1p0, Wself_p1, Wpp1, nullptr, nullptr, nullptr, 1,
               Wep1_pp, P1pp, P2pp};
    fa.d[1] = {h1a0, nullptr, CO_AAD, 16, nullptr,
               h1a0, Wself_a1, Waa1, nullptr, nullptr, nullptr, 1,
               Wep1_aa, P1aa, P2aa};
    fa.bstart[0] = 0; fa.bstart[1] = 512; fa.bstart[2] = 768; fa.nd = 2;
    fused_layer<<<768, 256, 0, stream>>>(fa, cnt, entries);
  }

  // ---- JAX keys: key(42) -> split -> (kpp, kaa) (partitionable fold-in) ----
  uint32_t kpp0, kpp1, kaa0, kaa1;
  { uint32_t a0 = 0, a1 = 0; tf2x32(0u, 42u, a0, a1); kpp0 = a0; kpp1 = a1; }
  { uint32_t a0 = 0, a1 = 1; tf2x32(0u, 42u, a0, a1); kaa0 = a0; kaa1 = a1; }

  // ---- fused edge-pred + sparse coalesce + gumbel top-5 + w write (wave-per-row) ----
  row_topk<<<(NPn + NAn) / 4, 256, 0, stream>>>(P1pp, P2pp, bep1_pp, Wep2_pp, bep2_pp,
                                                P1aa, P2aa, bep1_aa, Wep2_aa, bep2_aa,
                                                cnt, entries, w_pp_out, w_aa_out,
                                                kpp0, kpp1, kaa0, kaa1);

  // ---- K3: GNN2-L0 fused (weighted agg + 3-part gemm; Map/Mpa from K1) ----
  {
    FArgs fa{};
    fa.d[0] = {x_p, w_pp_out, CO_PPD, 18, nullptr,
               x_p, Wself_p0, Wpp0, Map, Wap0, h2p0, 1,
               nullptr, nullptr, nullptr};
    fa.d[1] = {x_a, w_aa_out, CO_AAD, 16, nullptr,
               x_a, Wself_a0, Waa0, Mpa, Wpa0, h2a0, 1,
               nullptr, nullptr, nullptr};
    fa.bstart[0] = 0; fa.bstart[1] = 512; fa.bstart[2] = 768; fa.nd = 2;
    fused_layer<<<768, 256, 0, stream>>>(fa, cnt, entries);
  }

  // ---- GNN2 layer 1 only needed at one paper row -> fused with classifier ----
  final_kernel<<<1, 128, 0, stream>>>(h2p0, h2a0, idxPtr, w_pp_out,
                                      cnt, entries,
                                      Wself_p1, Wpp1, Wap1, Wc, bc, out);
}